// Round 4
// baseline (38.510 us; speedup 1.0000x reference)
//
#include <hip/hip_runtime.h>

#define D_IN  512
#define C_OUT 128
#define HW    16384   // 128*128 per batch
#define BM    128
#define BK    64
#define PAD   72      // 144B row stride -> exactly 2-way LDS aliasing on b128 reads (free, m136)
#define NT    (D_IN / BK)   // 8 K-steps

typedef __attribute__((ext_vector_type(8))) short bf16x8;
typedef __attribute__((ext_vector_type(4))) float f32x4;

__device__ __forceinline__ ushort f2bf(float f) {
    uint32_t u = __builtin_bit_cast(uint32_t, f);
    uint32_t r = (u + 0x7fffu + ((u >> 16) & 1u)) >> 16;  // RNE
    return (ushort)r;
}

__global__ __launch_bounds__(512, 4) void cwp_gemm(
    const float* __restrict__ x, const float* __restrict__ W,
    const float* __restrict__ bias, float* __restrict__ out)
{
    // double-buffered bf16 tiles: 2 * (128*72 + 128*72) * 2B = 72 KiB -> 2 blocks/CU
    __shared__ ushort Ws[2][C_OUT * PAD];   // [c][k]
    __shared__ ushort Xs[2][BM * PAD];      // [m][k]

    const int t    = threadIdx.x;
    const int lane = t & 63;
    const int wid  = t >> 6;     // 0..7
    const int wr   = wid >> 2;   // 0..1 : c-half   (64 channels each)
    const int wc   = wid & 3;    // 0..3 : m-quarter (32 rows each)
    const int q    = lane >> 4;  // 0..3
    const int lr   = lane & 15;

    const int m0   = blockIdx.x * BM;
    const int bidx = m0 / HW;
    const int hw0  = m0 % HW;

    const int srow = t >> 4;     // 0..31 staging row-within-pass
    const int scol = t & 15;     // f32x4 column within BK

    f32x4 acc[4][2];
    #pragma unroll
    for (int i = 0; i < 4; ++i)
        #pragma unroll
        for (int j = 0; j < 2; ++j)
            acc[i][j] = (f32x4){0.f, 0.f, 0.f, 0.f};

    f32x4 wv[4], xv[4];

    // ---- prologue: load + stage tile 0 ----
    #pragma unroll
    for (int p = 0; p < 4; ++p) {
        const int r = p * 32 + srow;
        wv[p] = *reinterpret_cast<const f32x4*>(&W[r * D_IN + scol * 4]);
        xv[p] = __builtin_nontemporal_load(
                    reinterpret_cast<const f32x4*>(&x[(size_t)(m0 + r) * D_IN + scol * 4]));
    }
    #pragma unroll
    for (int p = 0; p < 4; ++p) {
        const int r = p * 32 + srow;
        *reinterpret_cast<ushort4*>(&Ws[0][r * PAD + scol * 4]) =
            make_ushort4(f2bf(wv[p][0]), f2bf(wv[p][1]), f2bf(wv[p][2]), f2bf(wv[p][3]));
        *reinterpret_cast<ushort4*>(&Xs[0][r * PAD + scol * 4]) =
            make_ushort4(f2bf(xv[p][0]), f2bf(xv[p][1]), f2bf(xv[p][2]), f2bf(xv[p][3]));
    }
    __syncthreads();

    for (int k = 0; k < NT; ++k) {
        const int cur = k & 1;

        // ---- issue next tile's global loads (latency hides under compute) ----
        if (k + 1 < NT) {
            const int kt = (k + 1) * BK;
            #pragma unroll
            for (int p = 0; p < 4; ++p) {
                const int r = p * 32 + srow;
                wv[p] = *reinterpret_cast<const f32x4*>(&W[r * D_IN + kt + scol * 4]);
                xv[p] = __builtin_nontemporal_load(
                            reinterpret_cast<const f32x4*>(&x[(size_t)(m0 + r) * D_IN + kt + scol * 4]));
            }
        }

        // ---- compute tile k from buf[cur] ----
        #pragma unroll
        for (int ks = 0; ks < 2; ++ks) {
            bf16x8 af[4], bfv[2];
            #pragma unroll
            for (int i = 0; i < 4; ++i)
                af[i]  = *reinterpret_cast<const bf16x8*>(&Ws[cur][(wr*64 + i*16 + lr) * PAD + ks*32 + q*8]);
            #pragma unroll
            for (int j = 0; j < 2; ++j)
                bfv[j] = *reinterpret_cast<const bf16x8*>(&Xs[cur][(wc*32 + j*16 + lr) * PAD + ks*32 + q*8]);
            #pragma unroll
            for (int i = 0; i < 4; ++i)
                #pragma unroll
                for (int j = 0; j < 2; ++j)
                    acc[i][j] = __builtin_amdgcn_mfma_f32_16x16x32_bf16(af[i], bfv[j], acc[i][j], 0, 0, 0);
        }

        // ---- stage tile k+1 into buf[cur^1]; single barrier per K-step ----
        // hazard: buf[cur^1] was last READ by compute(k-1), separated by the
        // trailing barrier of iteration k-1. write->read of buf[cur^1] is
        // covered by the barrier below.
        if (k + 1 < NT) {
            #pragma unroll
            for (int p = 0; p < 4; ++p) {
                const int r = p * 32 + srow;
                *reinterpret_cast<ushort4*>(&Ws[cur^1][r * PAD + scol * 4]) =
                    make_ushort4(f2bf(wv[p][0]), f2bf(wv[p][1]), f2bf(wv[p][2]), f2bf(wv[p][3]));
                *reinterpret_cast<ushort4*>(&Xs[cur^1][r * PAD + scol * 4]) =
                    make_ushort4(f2bf(xv[p][0]), f2bf(xv[p][1]), f2bf(xv[p][2]), f2bf(xv[p][3]));
            }
            __syncthreads();
        }
    }

    // ---- epilogue: D row = c-local ((lane>>4)*4 + jj), col = m-local (lane&15) ----
    float* outb = out + (size_t)bidx * C_OUT * HW;
    #pragma unroll
    for (int i = 0; i < 4; ++i) {
        const int c0 = wr*64 + i*16 + q*4;
        #pragma unroll
        for (int j = 0; j < 2; ++j) {
            const int m = hw0 + wc*32 + j*16 + lr;
            #pragma unroll
            for (int jj = 0; jj < 4; ++jj) {
                const float v = acc[i][j][jj] + bias[c0 + jj];
                __builtin_nontemporal_store(v, &outb[(size_t)(c0 + jj) * HW + m]);
            }
        }
    }
}

extern "C" void kernel_launch(void* const* d_in, const int* in_sizes, int n_in,
                              void* d_out, int out_size, void* d_ws, size_t ws_size,
                              hipStream_t stream) {
    const float* x    = (const float*)d_in[0];
    const float* W    = (const float*)d_in[1];
    const float* b    = (const float*)d_in[2];
    float* out        = (float*)d_out;
    const int M = 4 * HW;              // 65536 rows
    dim3 grid(M / BM);                 // 512 blocks, 2 per CU
    cwp_gemm<<<grid, 512, 0, stream>>>(x, W, b, out);
}

// Round 5
// 33.001 us; speedup vs baseline: 1.1669x; 1.1669x over previous
//
#include <hip/hip_runtime.h>
#include <hip/hip_bf16.h>

#define D_IN  512
#define C_OUT 128
#define HW    16384   // 128*128 per batch
#define BM    64
#define BK    64
#define PAD   72      // 144B row stride -> 2-way LDS aliasing on b128 reads (free, m136)
#define NTK   (D_IN / BK)   // 8 K-steps

typedef __attribute__((ext_vector_type(8))) short bf16x8;
typedef __attribute__((ext_vector_type(4))) float f32x4;

__device__ __forceinline__ ushort bf(float f) {
    // scalar cast -> compiler emits v_cvt_pk_bf16_f32 pairs (RNE), per m240
    return __builtin_bit_cast(ushort, __float2bfloat16(f));
}

__global__ __launch_bounds__(256, 4) void cwp_gemm(
    const float* __restrict__ x, const float* __restrict__ W,
    const float* __restrict__ bias, float* __restrict__ out)
{
    __shared__ ushort Ws[C_OUT * PAD];   // 18 KB  [c][k] bf16
    __shared__ ushort Xs[BM * PAD];      //  9 KB  [m][k] bf16

    const int t    = threadIdx.x;
    const int lane = t & 63;
    const int wid  = t >> 6;     // 0..3
    const int wr   = wid >> 1;   // 0..1 : c-half  (64 channels)
    const int wc   = wid & 1;    // 0..1 : m-half  (32 rows)
    const int q    = lane >> 4;  // 0..3
    const int lr   = lane & 15;

    const int m0   = blockIdx.x * BM;
    const int bidx = m0 / HW;
    const int hw0  = m0 % HW;

    const int srow = t >> 4;     // 0..15 staging row base
    const int scol = t & 15;     // f32x4 column within BK

    f32x4 acc[4][2];
    #pragma unroll
    for (int i = 0; i < 4; ++i)
        #pragma unroll
        for (int j = 0; j < 2; ++j)
            acc[i][j] = (f32x4){0.f, 0.f, 0.f, 0.f};

    for (int k = 0; k < NTK; ++k) {
        const int kt = k * BK;

        // ---- staging loads: 8 f32x4 of W (128 rows) + 4 f32x4 of x (64 rows) ----
        f32x4 wv[8], xv[4];
        #pragma unroll
        for (int p = 0; p < 8; ++p) {
            const int r = p * 16 + srow;
            wv[p] = *reinterpret_cast<const f32x4*>(&W[r * D_IN + kt + scol * 4]);
        }
        #pragma unroll
        for (int p = 0; p < 4; ++p) {
            const int r = p * 16 + srow;
            xv[p] = *reinterpret_cast<const f32x4*>(&x[(size_t)(m0 + r) * D_IN + kt + scol * 4]);
        }
        __syncthreads();  // previous tile's compute done before LDS overwrite
        #pragma unroll
        for (int p = 0; p < 8; ++p) {
            const int r = p * 16 + srow;
            *reinterpret_cast<ushort4*>(&Ws[r * PAD + scol * 4]) =
                make_ushort4(bf(wv[p][0]), bf(wv[p][1]), bf(wv[p][2]), bf(wv[p][3]));
        }
        #pragma unroll
        for (int p = 0; p < 4; ++p) {
            const int r = p * 16 + srow;
            *reinterpret_cast<ushort4*>(&Xs[r * PAD + scol * 4]) =
                make_ushort4(bf(xv[p][0]), bf(xv[p][1]), bf(xv[p][2]), bf(xv[p][3]));
        }
        __syncthreads();

        // ---- compute: 2 k-subs x 8 MFMA per wave ----
        #pragma unroll
        for (int ks = 0; ks < 2; ++ks) {
            bf16x8 af[4], bfv[2];
            #pragma unroll
            for (int i = 0; i < 4; ++i)
                af[i]  = *reinterpret_cast<const bf16x8*>(&Ws[(wr*64 + i*16 + lr) * PAD + ks*32 + q*8]);
            #pragma unroll
            for (int j = 0; j < 2; ++j)
                bfv[j] = *reinterpret_cast<const bf16x8*>(&Xs[(wc*32 + j*16 + lr) * PAD + ks*32 + q*8]);
            #pragma unroll
            for (int i = 0; i < 4; ++i)
                #pragma unroll
                for (int j = 0; j < 2; ++j)
                    acc[i][j] = __builtin_amdgcn_mfma_f32_16x16x32_bf16(af[i], bfv[j], acc[i][j], 0, 0, 0);
        }
    }

    // ---- epilogue: D row = c-local (q*4 + jj), col = m-local (lane&15) ----
    float* outb = out + (size_t)bidx * C_OUT * HW;
    #pragma unroll
    for (int i = 0; i < 4; ++i) {
        const int c0 = wr*64 + i*16 + q*4;
        #pragma unroll
        for (int j = 0; j < 2; ++j) {
            const int m = hw0 + wc*32 + j*16 + lr;
            #pragma unroll
            for (int jj = 0; jj < 4; ++jj)
                outb[(size_t)(c0 + jj) * HW + m] = acc[i][j][jj] + bias[c0 + jj];
        }
    }
}

extern "C" void kernel_launch(void* const* d_in, const int* in_sizes, int n_in,
                              void* d_out, int out_size, void* d_ws, size_t ws_size,
                              hipStream_t stream) {
    const float* x    = (const float*)d_in[0];
    const float* W    = (const float*)d_in[1];
    const float* b    = (const float*)d_in[2];
    float* out        = (float*)d_out;
    const int M = 4 * HW;              // 65536 rows
    dim3 grid(M / BM);                 // 1024 blocks -> 4 per CU
    cwp_gemm<<<grid, 256, 0, stream>>>(x, W, b, out);
}